// Round 5
// baseline (3898.016 us; speedup 1.0000x reference)
//
#include <hip/hip_runtime.h>
#include <hip/hip_bf16.h>
#include <math.h>

#define HH 32
#define LL 3
#define DS 512
#define DID 128
#define DSTEER 1664
#define DHID 2048
#define HDQ 1024
#define BHROWS 32768

typedef __attribute__((ext_vector_type(8))) short short8;
typedef __attribute__((ext_vector_type(4))) float f32x4;

typedef const __attribute__((address_space(1))) unsigned int* gptr_t;
typedef __attribute__((address_space(3))) unsigned int* lptr_t;

#define FENCE() asm volatile("" ::: "memory")
#define BAR() do { FENCE(); __builtin_amdgcn_s_barrier(); FENCE(); } while (0)
#define VMCNT8()  asm volatile("s_waitcnt vmcnt(8)" ::: "memory")
#define VMCNT4()  asm volatile("s_waitcnt vmcnt(4)" ::: "memory")
#define VMCNT2()  asm volatile("s_waitcnt vmcnt(2)" ::: "memory")
#define VMCNT0()  asm volatile("s_waitcnt vmcnt(0)" ::: "memory")
#define VMNOP()   do {} while (0)
#define LGKM(n) do { asm volatile("s_waitcnt lgkmcnt(" #n ")" ::: "memory"); \
                     __builtin_amdgcn_sched_barrier(0); } while (0)

__device__ __forceinline__ unsigned short f2bf(float f) {
  union { float f; unsigned int u; } x; x.f = f;
  unsigned int r = (x.u + 0x7FFFu + ((x.u >> 16) & 1u)) >> 16;
  return (unsigned short)r;
}
__device__ __forceinline__ unsigned int pk2(float a, float b) {
  return (unsigned int)f2bf(a) | ((unsigned int)f2bf(b) << 16);
}
__device__ __forceinline__ float gelu_exact(float v) {
  return 0.5f * v * (1.0f + erff(v * 0.70710678118654752440f));
}

// ---------- fp32 -> bf16 bulk convert ----------
__global__ void cvt_bf16_kernel(const float4* __restrict__ in, uint2* __restrict__ out, long n4) {
  long i = (long)blockIdx.x * blockDim.x + threadIdx.x;
  long stride = (long)gridDim.x * blockDim.x;
  for (; i < n4; i += stride) {
    float4 v = in[i];
    uint2 o; o.x = pk2(v.x, v.y); o.y = pk2(v.z, v.w);
    out[i] = o;
  }
}

// ---------- batched transpose + convert: fp32 [R][C] -> bf16 [C][R] ----------
__global__ void transpose_cvt_kernel(const float* __restrict__ in, long long in_bstride,
                                     unsigned short* __restrict__ out, long long out_bstride,
                                     int R, int C) {
  __shared__ float t[64][33];
  const int r0 = blockIdx.y * 32;
  const int c0 = blockIdx.x * 64;
  const float* bin = in + (long long)blockIdx.z * in_bstride;
  unsigned short* bout = out + (long long)blockIdx.z * out_bstride;
  const int tid = threadIdx.x;
  const int col = tid & 63, rr = tid >> 6;
  #pragma unroll
  for (int j = 0; j < 8; j++) {
    int r = j * 4 + rr;
    t[col][r] = bin[(size_t)(r0 + r) * C + c0 + col];
  }
  __syncthreads();
  const int rq = (tid & 7) * 4;
  const int cc = tid >> 3;
  #pragma unroll
  for (int j = 0; j < 2; j++) {
    int c = j * 32 + cc;
    float v0 = t[c][rq], v1 = t[c][rq + 1], v2 = t[c][rq + 2], v3 = t[c][rq + 3];
    uint2 o; o.x = pk2(v0, v1); o.y = pk2(v2, v3);
    *(uint2*)&bout[(size_t)(c0 + c) * R + r0 + rq] = o;
  }
}

// ---------- RMS-norm + scale -> bf16 ----------
__global__ void rms_scale_kernel(const float* __restrict__ h,
                                 const float* __restrict__ norm_w,
                                 unsigned short* __restrict__ xn, int layer) {
  int gw = (int)((blockIdx.x * blockDim.x + threadIdx.x) >> 6);
  int lane = threadIdx.x & 63;
  if (gw >= BHROWS) return;
  int head = gw & (HH - 1);
  const float4* hr = (const float4*)(h + (size_t)gw * DS);
  float4 v0 = hr[lane * 2], v1 = hr[lane * 2 + 1];
  float ss = v0.x*v0.x + v0.y*v0.y + v0.z*v0.z + v0.w*v0.w
           + v1.x*v1.x + v1.y*v1.y + v1.z*v1.z + v1.w*v1.w;
  #pragma unroll
  for (int off = 32; off > 0; off >>= 1) ss += __shfl_xor(ss, off, 64);
  float r = rsqrtf(ss * (1.0f / DS) + 1e-6f);
  const float4* nw = (const float4*)(norm_w + ((size_t)head * LL + layer) * DS);
  float4 w0 = nw[lane * 2], w1 = nw[lane * 2 + 1];
  uint4 o;
  o.x = pk2(v0.x * r * w0.x, v0.y * r * w0.y);
  o.y = pk2(v0.z * r * w0.z, v0.w * r * w0.w);
  o.z = pk2(v1.x * r * w1.x, v1.y * r * w1.y);
  o.w = pk2(v1.z * r * w1.z, v1.w * r * w1.w);
  *(uint4*)(xn + (size_t)gw * DS + (size_t)lane * 8) = o;
}

// ---------- 256x256 tile, BK=64, 8-wave, quadrant-pipelined bf16 GEMM ----------
// Geometry/swizzle/staging identical to prior passing kernel. Schedule: each
// phase issues the NEXT quadrant's ds_reads before its own MFMA cluster, so
// LDS read service overlaps MFMA. One barrier per phase. T = K/64 (always even).
// Quadrants: Q00(a,b01) Q01(a,b23) Q11(a',b23) Q10(a',b01).
// Stages/tile: P0:A1(t+1) P1:A0(t+2) P2:B0(t+2) P3:B1(t+2); waits vmcnt(8)
// at end-P0/P2/P3 each retiring loads issued >=4 phases earlier.
template<int EPI>
__global__ __launch_bounds__(512, 2)
void gemm256_kernel(const unsigned short* __restrict__ A, int lda, int rstep,
                    const unsigned short* __restrict__ Bt, int ldb, long long b_hstride,
                    const float* __restrict__ bias, int bias_hstride,
                    const float* __restrict__ resid, int ldr,
                    void* __restrict__ Cv, int ldc, int K) {
  __shared__ unsigned short lds[2 * 2 * 256 * 64];  // 128 KiB
  const int tid = threadIdx.x;
  const int lane = tid & 63;
  const int wave = tid >> 6;
  const int wr = wave >> 2, wc = wave & 3;
  const int head = blockIdx.z;
  const int gx = gridDim.x;
  const int nwg = gx * gridDim.y;
  int wgid = blockIdx.y * gx + blockIdx.x;
  { int cpx = nwg >> 3; wgid = (wgid & 7) * cpx + (wgid >> 3); }  // bijective: nwg%8==0
  const int tn = wgid % gx, tm = wgid / gx;

  // ---- staging addressing (per-lane source, linear LDS dest) ----
  const int l3 = lane >> 3;                   // 0..7
  const int gslot = ((lane & 7) ^ l3) * 8;    // inverse-swizzled k offset (elements)
  const int mbase = wave * 8 + l3;
  const int nbase = (wave >> 2) * 64 + (wave & 3) * 8 + l3;
  const unsigned short* pA = A + ((size_t)(tm * 256 + mbase) * rstep + head) * lda + gslot;
  const unsigned short* pB = Bt + (size_t)head * b_hstride
                               + (size_t)(tn * 256 + nbase) * ldb + gslot;
  const size_t aBlk = (size_t)64 * rstep * lda;

  // ---- fragment read addressing ----
  const int physk0 = ((lane >> 4) ^ (lane & 7)) * 8;
  const int physk1 = ((4 + (lane >> 4)) ^ (lane & 7)) * 8;
  const int aRow = wr * 128 + (lane & 15);
  const int bRow = wc * 32 + (lane & 15);

  auto stageA = [&](unsigned short* dstA, int h, size_t kels) {
    #pragma unroll
    for (int i = 0; i < 2; ++i)
      __builtin_amdgcn_global_load_lds(
          (gptr_t)(pA + (size_t)(i * 2 + h) * aBlk + kels),
          (lptr_t)(dstA + ((i * 2 + h) * 64 + wave * 8) * 64), 16, 0, 0);
  };
  auto stageB = [&](unsigned short* dstB, int h, size_t kels) {
    #pragma unroll
    for (int i = 0; i < 2; ++i)
      __builtin_amdgcn_global_load_lds(
          (gptr_t)(pB + (size_t)(i * 128 + h * 32) * ldb + kels),
          (lptr_t)(dstB + (h * 128 + i * 64 + wave * 8) * 64), 16, 0, 0);
  };

  f32x4 acc[8][4];
  #pragma unroll
  for (int i = 0; i < 8; ++i)
    #pragma unroll
    for (int j = 0; j < 4; ++j) acc[i][j] = (f32x4){0.f, 0.f, 0.f, 0.f};
  short8 aA[4][2], aB[4][2], bA[2][2], bB[2][2];

#define MFMA_Q(MO, NO, AR, BR) do { \
    __builtin_amdgcn_s_setprio(1); \
    _Pragma("unroll") \
    for (int i_ = 0; i_ < 4; ++i_) { \
      _Pragma("unroll") \
      for (int j_ = 0; j_ < 2; ++j_) { \
        acc[(MO)+i_][(NO)+j_] = __builtin_amdgcn_mfma_f32_16x16x32_bf16( \
            AR[i_][0], BR[j_][0], acc[(MO)+i_][(NO)+j_], 0, 0, 0); \
        acc[(MO)+i_][(NO)+j_] = __builtin_amdgcn_mfma_f32_16x16x32_bf16( \
            AR[i_][1], BR[j_][1], acc[(MO)+i_][(NO)+j_], 0, 0, 0); \
      } \
    } \
    __builtin_amdgcn_s_setprio(0); \
  } while (0)

  // LO always holds b01(t); HI gets b23(t) then b01(t+1).
#define TILE(tt, LO, HI, PAR, M1, M2, VMP0, VMP2, VMP3) { \
    unsigned short* rA = lds + (PAR) * 32768; \
    unsigned short* rB = rA + 16384; \
    unsigned short* nA = lds + ((PAR) ^ 1) * 32768; \
    unsigned short* nB = nA + 16384; \
    const size_t k1_ = (size_t)((tt) + 1) * 64; \
    const size_t k2_ = (size_t)((tt) + 2) * 64; \
    /* P0: issue b23(t)->HI; stage A1(t+1); wait a,b01; MFMA Q00 */ \
    HI[0][0] = *(const short8*)&rB[(128 + bRow) * 64 + physk0]; \
    HI[0][1] = *(const short8*)&rB[(128 + bRow) * 64 + physk1]; \
    HI[1][0] = *(const short8*)&rB[(144 + bRow) * 64 + physk0]; \
    HI[1][1] = *(const short8*)&rB[(144 + bRow) * 64 + physk1]; \
    if (M1) stageA(nA, 1, k1_); \
    LGKM(4); \
    MFMA_Q(0, 0, aA, LO); \
    VMP0; BAR(); \
    /* P1: issue a'(t)->aB; stage A0(t+2); wait b23; MFMA Q01 */ \
    _Pragma("unroll") \
    for (int i_ = 0; i_ < 4; ++i_) { \
      aB[i_][0] = *(const short8*)&rA[(aRow + (4 + i_) * 16) * 64 + physk0]; \
      aB[i_][1] = *(const short8*)&rA[(aRow + (4 + i_) * 16) * 64 + physk1]; \
    } \
    if (M2) stageA(rA, 0, k2_); \
    LGKM(8); \
    MFMA_Q(0, 2, aA, HI); \
    BAR(); \
    /* P2: stage B0(t+2); wait a'; MFMA Q11 */ \
    if (M2) stageB(rB, 0, k2_); \
    LGKM(0); \
    MFMA_Q(4, 2, aB, HI); \
    VMP2; BAR(); \
    /* P3: issue a(t+1)->aA, b01(t+1)->HI; stage B1(t+2); MFMA Q10 (no lgkm wait) */ \
    if (M1) { \
      _Pragma("unroll") \
      for (int i_ = 0; i_ < 4; ++i_) { \
        aA[i_][0] = *(const short8*)&nA[(aRow + i_ * 16) * 64 + physk0]; \
        aA[i_][1] = *(const short8*)&nA[(aRow + i_ * 16) * 64 + physk1]; \
      } \
      HI[0][0] = *(const short8*)&nB[(bRow) * 64 + physk0]; \
      HI[0][1] = *(const short8*)&nB[(bRow) * 64 + physk1]; \
      HI[1][0] = *(const short8*)&nB[(bRow + 16) * 64 + physk0]; \
      HI[1][1] = *(const short8*)&nB[(bRow + 16) * 64 + physk1]; \
      __builtin_amdgcn_sched_barrier(0); \
    } \
    if (M2) stageB(rB, 1, k2_); \
    MFMA_Q(4, 0, aB, LO); \
    VMP3; BAR(); \
  }

  const int T = K >> 6;  // always even for our shapes
  // ---- prologue ----
  stageA(lds, 0, 0);           // A0(0)
  stageB(lds + 16384, 0, 0);   // B0(0)
  stageB(lds + 16384, 1, 0);   // B1(0)
  VMCNT0();
  BAR();
  #pragma unroll
  for (int i = 0; i < 4; ++i) {
    aA[i][0] = *(const short8*)&lds[(aRow + i * 16) * 64 + physk0];
    aA[i][1] = *(const short8*)&lds[(aRow + i * 16) * 64 + physk1];
  }
  bA[0][0] = *(const short8*)&lds[(16384 / 1) + 0];  // placeholder overwritten below
  bA[0][0] = *(const short8*)&lds[16384 + (bRow) * 64 + physk0];
  bA[0][1] = *(const short8*)&lds[16384 + (bRow) * 64 + physk1];
  bA[1][0] = *(const short8*)&lds[16384 + (bRow + 16) * 64 + physk0];
  bA[1][1] = *(const short8*)&lds[16384 + (bRow + 16) * 64 + physk1];
  stageA(lds, 1, 0);                    // A1(0)
  stageA(lds + 32768, 0, 64);           // A0(1)
  stageB(lds + 32768 + 16384, 0, 64);   // B0(1)
  stageB(lds + 32768 + 16384, 1, 64);   // B1(1)

  // ---- main loop: pairs with all flags true ----
  for (int t = 0; t + 3 < T; t += 2) {
    TILE(t,     bA, bB, 0, 1, 1, VMCNT8(), VMCNT8(), VMCNT8());
    TILE(t + 1, bB, bA, 1, 1, 1, VMCNT8(), VMCNT8(), VMCNT8());
  }
  // ---- peeled tail: tiles T-2 (even parity) and T-1 (odd) ----
  TILE(T - 2, bA, bB, 0, 1, 0, VMCNT8(), VMCNT4(), VMCNT2());
  TILE(T - 1, bB, bA, 1, 0, 0, VMCNT0(), VMNOP(), VMNOP());

#undef TILE
#undef MFMA_Q

  // ---- epilogue ----
  const float* bptr = bias + (size_t)head * bias_hstride;
  #pragma unroll
  for (int i = 0; i < 8; ++i) {
    #pragma unroll
    for (int j = 0; j < 4; ++j) {
      #pragma unroll
      for (int r = 0; r < 4; ++r) {
        int rowt = wr * 128 + i * 16 + (lane >> 4) * 4 + r;
        int colt = wc * 64 + j * 16 + (lane & 15);
        int col = tn * 256 + colt;
        size_t crow = (size_t)(tm * 256 + rowt) * rstep + head;
        float v = acc[i][j][r] + bptr[col];
        if (EPI == 1) {
          ((unsigned short*)Cv)[crow * (size_t)ldc + col] = f2bf(gelu_exact(v));
        } else if (EPI == 2) {
          v += resid[crow * (size_t)ldr + col];
          ((float*)Cv)[crow * (size_t)ldc + col] = v;
        } else {
          ((float*)Cv)[crow * (size_t)ldc + col] = v;
        }
      }
    }
  }
}

extern "C" void kernel_launch(void* const* d_in, const int* in_sizes, int n_in,
                              void* d_out, int out_size, void* d_ws, size_t ws_size,
                              hipStream_t stream) {
  const float* x         = (const float*)d_in[0];
  const float* id_in     = (const float*)d_in[1];
  const float* in_proj_w = (const float*)d_in[2];
  const float* in_proj_b = (const float*)d_in[3];
  const float* norm_w    = (const float*)d_in[4];
  const float* up_w      = (const float*)d_in[5];
  const float* up_b      = (const float*)d_in[6];
  const float* down_w    = (const float*)d_in[7];
  const float* down_b    = (const float*)d_in[8];
  const float* q1_w      = (const float*)d_in[9];
  const float* q1_b      = (const float*)d_in[10];
  const float* q2_w      = (const float*)d_in[11];
  const float* q2_b      = (const float*)d_in[12];
  const float* k1_w      = (const float*)d_in[13];
  const float* k1_b      = (const float*)d_in[14];
  const float* k2_w      = (const float*)d_in[15];
  const float* k2_b      = (const float*)d_in[16];
  float* out = (float*)d_out;

  char* ws = (char*)d_ws;
  unsigned short* x_bf  = (unsigned short*)ws; ws += (size_t)BHROWS * DSTEER * 2;  // 109 MB
  unsigned short* id_bf = (unsigned short*)ws; ws += (size_t)BHROWS * DID * 2;     // 8.4 MB
  float*          hbuf  = (float*)ws;          ws += (size_t)BHROWS * DS * 4;      // 67 MB
  unsigned short* xn    = (unsigned short*)ws; ws += (size_t)BHROWS * DS * 2;      // 33.5 MB
  unsigned short* hid   = (unsigned short*)ws; ws += (size_t)BHROWS * DHID * 2;    // 134 MB
  unsigned short* wbuf  = (unsigned short*)ws; ws += (size_t)HH * DHID * DS * 2;   // 67 MB (reused)

  // activations -> bf16
  cvt_bf16_kernel<<<2048, 256, 0, stream>>>((const float4*)x, (uint2*)x_bf,
                                            (long)BHROWS * DSTEER / 4);
  cvt_bf16_kernel<<<512, 256, 0, stream>>>((const float4*)id_in, (uint2*)id_bf,
                                           (long)BHROWS * DID / 4);

  // ---- q path ----
  transpose_cvt_kernel<<<dim3(2 * HDQ / 64, DSTEER / 32, 1), 256, 0, stream>>>(
      q1_w, 0, wbuf, 0, DSTEER, 2 * HDQ);
  gemm256_kernel<1><<<dim3(8, 128, 1), 512, 0, stream>>>(
      x_bf, DSTEER, 1, wbuf, DSTEER, 0, q1_b, 0, nullptr, 0, hid, 2 * HDQ, DSTEER);
  transpose_cvt_kernel<<<dim3(HDQ / 64, 2 * HDQ / 32, 1), 256, 0, stream>>>(
      q2_w, 0, wbuf, 0, 2 * HDQ, HDQ);
  gemm256_kernel<0><<<dim3(4, 128, 1), 512, 0, stream>>>(
      hid, 2 * HDQ, 1, wbuf, 2 * HDQ, 0, q2_b, 0, nullptr, 0, out + 512, 2560, 2 * HDQ);

  // ---- k path ----
  transpose_cvt_kernel<<<dim3(2 * HDQ / 64, DID / 32, 1), 256, 0, stream>>>(
      k1_w, 0, wbuf, 0, DID, 2 * HDQ);
  gemm256_kernel<1><<<dim3(8, 128, 1), 512, 0, stream>>>(
      id_bf, DID, 1, wbuf, DID, 0, k1_b, 0, nullptr, 0, hid, 2 * HDQ, DID);
  transpose_cvt_kernel<<<dim3(HDQ / 64, 2 * HDQ / 32, 1), 256, 0, stream>>>(
      k2_w, 0, wbuf, 0, 2 * HDQ, HDQ);
  gemm256_kernel<0><<<dim3(4, 128, 1), 512, 0, stream>>>(
      hid, 2 * HDQ, 1, wbuf, 2 * HDQ, 0, k2_b, 0, nullptr, 0, out + 1536, 2560, 2 * HDQ);

  // ---- content: in_proj (per-head) ----
  transpose_cvt_kernel<<<dim3(DS / 64, DSTEER / 32, HH), 256, 0, stream>>>(
      in_proj_w, (long long)DSTEER * DS, wbuf, (long long)DS * DSTEER, DSTEER, DS);
  gemm256_kernel<0><<<dim3(2, 4, 32), 512, 0, stream>>>(
      x_bf, DSTEER, HH, wbuf, DSTEER, (long long)DS * DSTEER, in_proj_b, DS,
      nullptr, 0, hbuf, DS, DSTEER);

  for (int i = 0; i < LL; i++) {
    rms_scale_kernel<<<8192, 256, 0, stream>>>(hbuf, norm_w, xn, i);
    transpose_cvt_kernel<<<dim3(DHID / 64, DS / 32, HH), 256, 0, stream>>>(
        up_w + (size_t)i * DS * DHID, (long long)LL * DS * DHID,
        wbuf, (long long)DHID * DS, DS, DHID);
    gemm256_kernel<1><<<dim3(8, 4, 32), 512, 0, stream>>>(
        xn, DS, HH, wbuf, DS, (long long)DHID * DS,
        up_b + (size_t)i * DHID, LL * DHID, nullptr, 0, hid, DHID, DS);
    transpose_cvt_kernel<<<dim3(DS / 64, DHID / 32, HH), 256, 0, stream>>>(
        down_w + (size_t)i * DHID * DS, (long long)LL * DHID * DS,
        wbuf, (long long)DS * DHID, DHID, DS);
    float* cout = (i < 2) ? hbuf : out;  // last layer -> out[:,0:512)
    int ldc = (i < 2) ? DS : 2560;
    gemm256_kernel<2><<<dim3(2, 4, 32), 512, 0, stream>>>(
        hid, DHID, HH, wbuf, DHID, (long long)DS * DHID,
        down_b + (size_t)i * DS, LL * DS, hbuf, DS, cout, ldc, DHID);
  }
}

// Round 6
// 1720.680 us; speedup vs baseline: 2.2654x; 2.2654x over previous
//
#include <hip/hip_runtime.h>
#include <hip/hip_bf16.h>
#include <math.h>

#define HH 32
#define LL 3
#define DS 512
#define DID 128
#define DSTEER 1664
#define DHID 2048
#define HDQ 1024
#define BHROWS 32768

typedef __attribute__((ext_vector_type(8))) short short8;
typedef __attribute__((ext_vector_type(4))) float f32x4;

typedef const __attribute__((address_space(1))) unsigned int* gptr_t;
typedef __attribute__((address_space(3))) unsigned int* lptr_t;

// m201-style sync: bare barrier, unclobbered counted waits, sched_barrier pins.
#define BAR() __builtin_amdgcn_s_barrier()
#define SB()  __builtin_amdgcn_sched_barrier(0)
#define VMCNT8() asm volatile("s_waitcnt vmcnt(8)")
#define VMCNT2() asm volatile("s_waitcnt vmcnt(2)")
#define VMCNT0() asm volatile("s_waitcnt vmcnt(0)")

__device__ __forceinline__ unsigned short f2bf(float f) {
  union { float f; unsigned int u; } x; x.f = f;
  unsigned int r = (x.u + 0x7FFFu + ((x.u >> 16) & 1u)) >> 16;
  return (unsigned short)r;
}
__device__ __forceinline__ unsigned int pk2(float a, float b) {
  return (unsigned int)f2bf(a) | ((unsigned int)f2bf(b) << 16);
}
__device__ __forceinline__ float gelu_exact(float v) {
  return 0.5f * v * (1.0f + erff(v * 0.70710678118654752440f));
}

// ---------- fp32 -> bf16 bulk convert ----------
__global__ void cvt_bf16_kernel(const float4* __restrict__ in, uint2* __restrict__ out, long n4) {
  long i = (long)blockIdx.x * blockDim.x + threadIdx.x;
  long stride = (long)gridDim.x * blockDim.x;
  for (; i < n4; i += stride) {
    float4 v = in[i];
    uint2 o; o.x = pk2(v.x, v.y); o.y = pk2(v.z, v.w);
    out[i] = o;
  }
}

// ---------- batched transpose + convert: fp32 [R][C] -> bf16 [C][R] ----------
__global__ void transpose_cvt_kernel(const float* __restrict__ in, long long in_bstride,
                                     unsigned short* __restrict__ out, long long out_bstride,
                                     int R, int C) {
  __shared__ float t[64][33];
  const int r0 = blockIdx.y * 32;
  const int c0 = blockIdx.x * 64;
  const float* bin = in + (long long)blockIdx.z * in_bstride;
  unsigned short* bout = out + (long long)blockIdx.z * out_bstride;
  const int tid = threadIdx.x;
  const int col = tid & 63, rr = tid >> 6;
  #pragma unroll
  for (int j = 0; j < 8; j++) {
    int r = j * 4 + rr;
    t[col][r] = bin[(size_t)(r0 + r) * C + c0 + col];
  }
  __syncthreads();
  const int rq = (tid & 7) * 4;
  const int cc = tid >> 3;
  #pragma unroll
  for (int j = 0; j < 2; j++) {
    int c = j * 32 + cc;
    float v0 = t[c][rq], v1 = t[c][rq + 1], v2 = t[c][rq + 2], v3 = t[c][rq + 3];
    uint2 o; o.x = pk2(v0, v1); o.y = pk2(v2, v3);
    *(uint2*)&bout[(size_t)(c0 + c) * R + r0 + rq] = o;
  }
}

// ---------- RMS-norm + scale -> bf16 ----------
__global__ void rms_scale_kernel(const float* __restrict__ h,
                                 const float* __restrict__ norm_w,
                                 unsigned short* __restrict__ xn, int layer) {
  int gw = (int)((blockIdx.x * blockDim.x + threadIdx.x) >> 6);
  int lane = threadIdx.x & 63;
  if (gw >= BHROWS) return;
  int head = gw & (HH - 1);
  const float4* hr = (const float4*)(h + (size_t)gw * DS);
  float4 v0 = hr[lane * 2], v1 = hr[lane * 2 + 1];
  float ss = v0.x*v0.x + v0.y*v0.y + v0.z*v0.z + v0.w*v0.w
           + v1.x*v1.x + v1.y*v1.y + v1.z*v1.z + v1.w*v1.w;
  #pragma unroll
  for (int off = 32; off > 0; off >>= 1) ss += __shfl_xor(ss, off, 64);
  float r = rsqrtf(ss * (1.0f / DS) + 1e-6f);
  const float4* nw = (const float4*)(norm_w + ((size_t)head * LL + layer) * DS);
  float4 w0 = nw[lane * 2], w1 = nw[lane * 2 + 1];
  uint4 o;
  o.x = pk2(v0.x * r * w0.x, v0.y * r * w0.y);
  o.y = pk2(v0.z * r * w0.z, v0.w * r * w0.w);
  o.z = pk2(v1.x * r * w1.x, v1.y * r * w1.y);
  o.w = pk2(v1.z * r * w1.z, v1.w * r * w1.w);
  *(uint4*)(xn + (size_t)gw * DS + (size_t)lane * 8) = o;
}

// ---------- 256x256 tile, BK=64, 8-wave, 4-phase pipelined bf16 GEMM ----------
// Geometry/swizzle/registers identical to the round-4 passing kernel. Sync
// rebuilt m201-style: bare s_barrier, unclobbered counted vmcnt, sched_barrier
// pins; lgkm waits left to the compiler. Stage plan (iter t):
//   P0: A1(t+1) | P2: A0(t+2)+B0(t+2) | P3: B1(t+2)
// -> every LDS WAR hazard has >=4 barriers of separation.
// Ledger (8 loads/tile in flight): end-P1 vmcnt(8) retires A1(t) [issued
// P0(t-1)]; end-P3 vmcnt(8) retires A0/B0/B1(t+1) [issued P2/P3(t-1)].
// Tails: t=T-2 end-P3 vmcnt(2); t=T-1 end-P1 vmcnt(0).
template<int EPI>
__global__ __launch_bounds__(512, 2)
void gemm256_kernel(const unsigned short* __restrict__ A, int lda, int rstep,
                    const unsigned short* __restrict__ Bt, int ldb, long long b_hstride,
                    const float* __restrict__ bias, int bias_hstride,
                    const float* __restrict__ resid, int ldr,
                    void* __restrict__ Cv, int ldc, int K) {
  __shared__ unsigned short lds[2 * 2 * 256 * 64];  // 128 KiB
  const int tid = threadIdx.x;
  const int lane = tid & 63;
  const int wave = tid >> 6;
  const int wr = wave >> 2, wc = wave & 3;
  const int head = blockIdx.z;
  const int gx = gridDim.x;
  const int nwg = gx * gridDim.y;
  int wgid = blockIdx.y * gx + blockIdx.x;
  { int cpx = nwg >> 3; wgid = (wgid & 7) * cpx + (wgid >> 3); }  // bijective: nwg%8==0
  const int tn = wgid % gx, tm = wgid / gx;

  // ---- staging addressing (per-lane source, linear LDS dest) ----
  const int l3 = lane >> 3;                   // 0..7
  const int gslot = ((lane & 7) ^ l3) * 8;    // inverse-swizzled k offset (elements)
  const int mbase = wave * 8 + l3;
  const int nbase = (wave >> 2) * 64 + (wave & 3) * 8 + l3;
  const unsigned short* pA = A + ((size_t)(tm * 256 + mbase) * rstep + head) * lda + gslot;
  const unsigned short* pB = Bt + (size_t)head * b_hstride
                               + (size_t)(tn * 256 + nbase) * ldb + gslot;
  const size_t aBlk = (size_t)64 * rstep * lda;

  // ---- fragment read addressing ----
  const int physk0 = ((lane >> 4) ^ (lane & 7)) * 8;
  const int physk1 = ((4 + (lane >> 4)) ^ (lane & 7)) * 8;
  const int aRow = wr * 128 + (lane & 15);
  const int bRow = wc * 32 + (lane & 15);

  auto stageA = [&](unsigned short* dstA, int h, size_t kels) {
    #pragma unroll
    for (int i = 0; i < 2; ++i)
      __builtin_amdgcn_global_load_lds(
          (gptr_t)(pA + (size_t)(i * 2 + h) * aBlk + kels),
          (lptr_t)(dstA + ((i * 2 + h) * 64 + wave * 8) * 64), 16, 0, 0);
  };
  auto stageB = [&](unsigned short* dstB, int h, size_t kels) {
    #pragma unroll
    for (int i = 0; i < 2; ++i)
      __builtin_amdgcn_global_load_lds(
          (gptr_t)(pB + (size_t)(i * 128 + h * 32) * ldb + kels),
          (lptr_t)(dstB + (h * 128 + i * 64 + wave * 8) * 64), 16, 0, 0);
  };

  f32x4 acc[8][4];
  #pragma unroll
  for (int i = 0; i < 8; ++i)
    #pragma unroll
    for (int j = 0; j < 4; ++j) acc[i][j] = (f32x4){0.f, 0.f, 0.f, 0.f};
  short8 a[4][2], b[4][2];

  const int T = K >> 6;  // >= 2 for all shapes used
  // ---- prologue: tile0 {A0,B0,B1,A1} + tile1 {A0,B0,B1} = 14 loads ----
  stageA(lds, 0, 0);
  stageB(lds + 16384, 0, 0);
  stageB(lds + 16384, 1, 0);
  stageA(lds, 1, 0);
  stageA(lds + 32768, 0, 64);
  stageB(lds + 32768 + 16384, 0, 64);
  stageB(lds + 32768 + 16384, 1, 64);
  SB();
  VMCNT8();   // A0(0),B0(0),B1(0) landed; {A1(0),A0(1),B0(1),B1(1)} in flight
  BAR();
  SB();

  for (int t = 0; t < T; ++t) {
    unsigned short* rA = lds + (t & 1) * 32768;
    unsigned short* rB = rA + 16384;
    unsigned short* nA = lds + ((t + 1) & 1) * 32768;
    const size_t k1 = (size_t)(t + 1) * 64;
    const size_t k2 = (size_t)(t + 2) * 64;
    const bool m1 = (t + 1 < T), m2 = (t + 2 < T);

    // ======== P0: read a=A0(t), b01=B0(t); stage A1(t+1); MFMA Q00 ========
    #pragma unroll
    for (int i = 0; i < 4; ++i) {
      a[i][0] = *(const short8*)&rA[(aRow + i * 16) * 64 + physk0];
      a[i][1] = *(const short8*)&rA[(aRow + i * 16) * 64 + physk1];
    }
    #pragma unroll
    for (int j = 0; j < 2; ++j) {
      b[j][0] = *(const short8*)&rB[(bRow + j * 16) * 64 + physk0];
      b[j][1] = *(const short8*)&rB[(bRow + j * 16) * 64 + physk1];
    }
    if (m1) stageA(nA, 1, k1);
    SB(); BAR(); SB();
    __builtin_amdgcn_s_setprio(1);
    #pragma unroll
    for (int i = 0; i < 4; ++i)
      #pragma unroll
      for (int j = 0; j < 2; ++j) {
        acc[i][j] = __builtin_amdgcn_mfma_f32_16x16x32_bf16(a[i][0], b[j][0], acc[i][j], 0, 0, 0);
        acc[i][j] = __builtin_amdgcn_mfma_f32_16x16x32_bf16(a[i][1], b[j][1], acc[i][j], 0, 0, 0);
      }
    __builtin_amdgcn_s_setprio(0);
    SB(); BAR(); SB();

    // ======== P1: read b23=B1(t); MFMA Q01; wait A1(t) ========
    #pragma unroll
    for (int j = 0; j < 2; ++j) {
      b[2 + j][0] = *(const short8*)&rB[(128 + bRow + j * 16) * 64 + physk0];
      b[2 + j][1] = *(const short8*)&rB[(128 + bRow + j * 16) * 64 + physk1];
    }
    SB(); BAR(); SB();
    __builtin_amdgcn_s_setprio(1);
    #pragma unroll
    for (int i = 0; i < 4; ++i)
      #pragma unroll
      for (int j = 0; j < 2; ++j) {
        acc[i][2 + j] = __builtin_amdgcn_mfma_f32_16x16x32_bf16(a[i][0], b[2 + j][0], acc[i][2 + j], 0, 0, 0);
        acc[i][2 + j] = __builtin_amdgcn_mfma_f32_16x16x32_bf16(a[i][1], b[2 + j][1], acc[i][2 + j], 0, 0, 0);
      }
    __builtin_amdgcn_s_setprio(0);
    SB();
    if (m1) { VMCNT8(); } else { VMCNT0(); }
    BAR(); SB();

    // ======== P2: read a'=A1(t); stage A0(t+2)+B0(t+2); MFMA Q11 ========
    #pragma unroll
    for (int i = 0; i < 4; ++i) {
      a[i][0] = *(const short8*)&rA[(aRow + (4 + i) * 16) * 64 + physk0];
      a[i][1] = *(const short8*)&rA[(aRow + (4 + i) * 16) * 64 + physk1];
    }
    if (m2) { stageA(rA, 0, k2); stageB(rB, 0, k2); }
    SB(); BAR(); SB();
    __builtin_amdgcn_s_setprio(1);
    #pragma unroll
    for (int i = 0; i < 4; ++i)
      #pragma unroll
      for (int j = 0; j < 2; ++j) {
        acc[4 + i][2 + j] = __builtin_amdgcn_mfma_f32_16x16x32_bf16(a[i][0], b[2 + j][0], acc[4 + i][2 + j], 0, 0, 0);
        acc[4 + i][2 + j] = __builtin_amdgcn_mfma_f32_16x16x32_bf16(a[i][1], b[2 + j][1], acc[4 + i][2 + j], 0, 0, 0);
      }
    __builtin_amdgcn_s_setprio(0);
    SB(); BAR(); SB();

    // ======== P3: stage B1(t+2); MFMA Q10; wait A0/B0/B1(t+1) ========
    if (m2) stageB(rB, 1, k2);
    SB(); BAR(); SB();
    __builtin_amdgcn_s_setprio(1);
    #pragma unroll
    for (int i = 0; i < 4; ++i)
      #pragma unroll
      for (int j = 0; j < 2; ++j) {
        acc[4 + i][j] = __builtin_amdgcn_mfma_f32_16x16x32_bf16(a[i][0], b[j][0], acc[4 + i][j], 0, 0, 0);
        acc[4 + i][j] = __builtin_amdgcn_mfma_f32_16x16x32_bf16(a[i][1], b[j][1], acc[4 + i][j], 0, 0, 0);
      }
    __builtin_amdgcn_s_setprio(0);
    SB();
    if (m2) { VMCNT8(); } else if (m1) { VMCNT2(); }
    BAR(); SB();
  }

  // ---- epilogue ----
  const float* bptr = bias + (size_t)head * bias_hstride;
  #pragma unroll
  for (int i = 0; i < 8; ++i) {
    #pragma unroll
    for (int j = 0; j < 4; ++j) {
      #pragma unroll
      for (int r = 0; r < 4; ++r) {
        int rowt = wr * 128 + i * 16 + (lane >> 4) * 4 + r;
        int colt = wc * 64 + j * 16 + (lane & 15);
        int col = tn * 256 + colt;
        size_t crow = (size_t)(tm * 256 + rowt) * rstep + head;
        float v = acc[i][j][r] + bptr[col];
        if (EPI == 1) {
          ((unsigned short*)Cv)[crow * (size_t)ldc + col] = f2bf(gelu_exact(v));
        } else if (EPI == 2) {
          v += resid[crow * (size_t)ldr + col];
          ((float*)Cv)[crow * (size_t)ldc + col] = v;
        } else {
          ((float*)Cv)[crow * (size_t)ldc + col] = v;
        }
      }
    }
  }
}

extern "C" void kernel_launch(void* const* d_in, const int* in_sizes, int n_in,
                              void* d_out, int out_size, void* d_ws, size_t ws_size,
                              hipStream_t stream) {
  const float* x         = (const float*)d_in[0];
  const float* id_in     = (const float*)d_in[1];
  const float* in_proj_w = (const float*)d_in[2];
  const float* in_proj_b = (const float*)d_in[3];
  const float* norm_w    = (const float*)d_in[4];
  const float* up_w      = (const float*)d_in[5];
  const float* up_b      = (const float*)d_in[6];
  const float* down_w    = (const float*)d_in[7];
  const float* down_b    = (const float*)d_in[8];
  const float* q1_w      = (const float*)d_in[9];
  const float* q1_b      = (const float*)d_in[10];
  const float* q2_w      = (const float*)d_in[11];
  const float* q2_b      = (const float*)d_in[12];
  const float* k1_w      = (const float*)d_in[13];
  const float* k1_b      = (const float*)d_in[14];
  const float* k2_w      = (const float*)d_in[15];
  const float* k2_b      = (const float*)d_in[16];
  float* out = (float*)d_out;

  char* ws = (char*)d_ws;
  unsigned short* x_bf  = (unsigned short*)ws; ws += (size_t)BHROWS * DSTEER * 2;  // 109 MB
  unsigned short* id_bf = (unsigned short*)ws; ws += (size_t)BHROWS * DID * 2;     // 8.4 MB
  float*          hbuf  = (float*)ws;          ws += (size_t)BHROWS * DS * 4;      // 67 MB
  unsigned short* xn    = (unsigned short*)ws; ws += (size_t)BHROWS * DS * 2;      // 33.5 MB
  unsigned short* hid   = (unsigned short*)ws; ws += (size_t)BHROWS * DHID * 2;    // 134 MB
  unsigned short* wbuf  = (unsigned short*)ws; ws += (size_t)HH * DHID * DS * 2;   // 67 MB (reused)

  // activations -> bf16
  cvt_bf16_kernel<<<2048, 256, 0, stream>>>((const float4*)x, (uint2*)x_bf,
                                            (long)BHROWS * DSTEER / 4);
  cvt_bf16_kernel<<<512, 256, 0, stream>>>((const float4*)id_in, (uint2*)id_bf,
                                           (long)BHROWS * DID / 4);

  // ---- q path ----
  transpose_cvt_kernel<<<dim3(2 * HDQ / 64, DSTEER / 32, 1), 256, 0, stream>>>(
      q1_w, 0, wbuf, 0, DSTEER, 2 * HDQ);
  gemm256_kernel<1><<<dim3(8, 128, 1), 512, 0, stream>>>(
      x_bf, DSTEER, 1, wbuf, DSTEER, 0, q1_b, 0, nullptr, 0, hid, 2 * HDQ, DSTEER);
  transpose_cvt_kernel<<<dim3(HDQ / 64, 2 * HDQ / 32, 1), 256, 0, stream>>>(
      q2_w, 0, wbuf, 0, 2 * HDQ, HDQ);
  gemm256_kernel<0><<<dim3(4, 128, 1), 512, 0, stream>>>(
      hid, 2 * HDQ, 1, wbuf, 2 * HDQ, 0, q2_b, 0, nullptr, 0, out + 512, 2560, 2 * HDQ);

  // ---- k path ----
  transpose_cvt_kernel<<<dim3(2 * HDQ / 64, DID / 32, 1), 256, 0, stream>>>(
      k1_w, 0, wbuf, 0, DID, 2 * HDQ);
  gemm256_kernel<1><<<dim3(8, 128, 1), 512, 0, stream>>>(
      id_bf, DID, 1, wbuf, DID, 0, k1_b, 0, nullptr, 0, hid, 2 * HDQ, DID);
  transpose_cvt_kernel<<<dim3(HDQ / 64, 2 * HDQ / 32, 1), 256, 0, stream>>>(
      k2_w, 0, wbuf, 0, 2 * HDQ, HDQ);
  gemm256_kernel<0><<<dim3(4, 128, 1), 512, 0, stream>>>(
      hid, 2 * HDQ, 1, wbuf, 2 * HDQ, 0, k2_b, 0, nullptr, 0, out + 1536, 2560, 2 * HDQ);

  // ---- content: in_proj (per-head) ----
  transpose_cvt_kernel<<<dim3(DS / 64, DSTEER / 32, HH), 256, 0, stream>>>(
      in_proj_w, (long long)DSTEER * DS, wbuf, (long long)DS * DSTEER, DSTEER, DS);
  gemm256_kernel<0><<<dim3(2, 4, 32), 512, 0, stream>>>(
      x_bf, DSTEER, HH, wbuf, DSTEER, (long long)DS * DSTEER, in_proj_b, DS,
      nullptr, 0, hbuf, DS, DSTEER);

  for (int i = 0; i < LL; i++) {
    rms_scale_kernel<<<8192, 256, 0, stream>>>(hbuf, norm_w, xn, i);
    transpose_cvt_kernel<<<dim3(DHID / 64, DS / 32, HH), 256, 0, stream>>>(
        up_w + (size_t)i * DS * DHID, (long long)LL * DS * DHID,
        wbuf, (long long)DHID * DS, DS, DHID);
    gemm256_kernel<1><<<dim3(8, 4, 32), 512, 0, stream>>>(
        xn, DS, HH, wbuf, DS, (long long)DHID * DS,
        up_b + (size_t)i * DHID, LL * DHID, nullptr, 0, hid, DHID, DS);
    transpose_cvt_kernel<<<dim3(DS / 64, DHID / 32, HH), 256, 0, stream>>>(
        down_w + (size_t)i * DHID * DS, (long long)LL * DHID * DS,
        wbuf, (long long)DS * DHID, DHID, DS);
    float* cout = (i < 2) ? hbuf : out;  // last layer -> out[:,0:512)
    int ldc = (i < 2) ? DS : 2560;
    gemm256_kernel<2><<<dim3(2, 4, 32), 512, 0, stream>>>(
        hid, DHID, HH, wbuf, DHID, (long long)DS * DHID,
        down_b + (size_t)i * DS, LL * DS, hbuf, DS, cout, ldc, DHID);
  }
}

// Round 7
// 1693.538 us; speedup vs baseline: 2.3017x; 1.0160x over previous
//
#include <hip/hip_runtime.h>
#include <hip/hip_bf16.h>
#include <math.h>

#define HH 32
#define LL 3
#define DS 512
#define DID 128
#define DSTEER 1664
#define DHID 2048
#define HDQ 1024
#define BHROWS 32768

typedef __attribute__((ext_vector_type(8))) short short8;
typedef __attribute__((ext_vector_type(4))) float f32x4;

typedef const __attribute__((address_space(1))) unsigned int* gptr_t;
typedef __attribute__((address_space(3))) unsigned int* lptr_t;

// bare barrier; counted waits pinned only on the consumer side (rule #18).
#define BAR() __builtin_amdgcn_s_barrier()
#define SB()  __builtin_amdgcn_sched_barrier(0)
#define VMCNT8() asm volatile("s_waitcnt vmcnt(8)")
#define VMCNT2() asm volatile("s_waitcnt vmcnt(2)")
#define VMCNT0() asm volatile("s_waitcnt vmcnt(0)")

__device__ __forceinline__ unsigned short f2bf(float f) {
  union { float f; unsigned int u; } x; x.f = f;
  unsigned int r = (x.u + 0x7FFFu + ((x.u >> 16) & 1u)) >> 16;
  return (unsigned short)r;
}
__device__ __forceinline__ unsigned int pk2(float a, float b) {
  return (unsigned int)f2bf(a) | ((unsigned int)f2bf(b) << 16);
}
__device__ __forceinline__ float gelu_exact(float v) {
  return 0.5f * v * (1.0f + erff(v * 0.70710678118654752440f));
}

// ---------- fp32 -> bf16 bulk convert ----------
__global__ void cvt_bf16_kernel(const float4* __restrict__ in, uint2* __restrict__ out, long n4) {
  long i = (long)blockIdx.x * blockDim.x + threadIdx.x;
  long stride = (long)gridDim.x * blockDim.x;
  for (; i < n4; i += stride) {
    float4 v = in[i];
    uint2 o; o.x = pk2(v.x, v.y); o.y = pk2(v.z, v.w);
    out[i] = o;
  }
}

// ---------- batched transpose + convert: fp32 [R][C] -> bf16 [C][R] ----------
__global__ void transpose_cvt_kernel(const float* __restrict__ in, long long in_bstride,
                                     unsigned short* __restrict__ out, long long out_bstride,
                                     int R, int C) {
  __shared__ float t[64][33];
  const int r0 = blockIdx.y * 32;
  const int c0 = blockIdx.x * 64;
  const float* bin = in + (long long)blockIdx.z * in_bstride;
  unsigned short* bout = out + (long long)blockIdx.z * out_bstride;
  const int tid = threadIdx.x;
  const int col = tid & 63, rr = tid >> 6;
  #pragma unroll
  for (int j = 0; j < 8; j++) {
    int r = j * 4 + rr;
    t[col][r] = bin[(size_t)(r0 + r) * C + c0 + col];
  }
  __syncthreads();
  const int rq = (tid & 7) * 4;
  const int cc = tid >> 3;
  #pragma unroll
  for (int j = 0; j < 2; j++) {
    int c = j * 32 + cc;
    float v0 = t[c][rq], v1 = t[c][rq + 1], v2 = t[c][rq + 2], v3 = t[c][rq + 3];
    uint2 o; o.x = pk2(v0, v1); o.y = pk2(v2, v3);
    *(uint2*)&bout[(size_t)(c0 + c) * R + r0 + rq] = o;
  }
}

// ---------- RMS-norm + scale -> bf16 ----------
__global__ void rms_scale_kernel(const float* __restrict__ h,
                                 const float* __restrict__ norm_w,
                                 unsigned short* __restrict__ xn, int layer) {
  int gw = (int)((blockIdx.x * blockDim.x + threadIdx.x) >> 6);
  int lane = threadIdx.x & 63;
  if (gw >= BHROWS) return;
  int head = gw & (HH - 1);
  const float4* hr = (const float4*)(h + (size_t)gw * DS);
  float4 v0 = hr[lane * 2], v1 = hr[lane * 2 + 1];
  float ss = v0.x*v0.x + v0.y*v0.y + v0.z*v0.z + v0.w*v0.w
           + v1.x*v1.x + v1.y*v1.y + v1.z*v1.z + v1.w*v1.w;
  #pragma unroll
  for (int off = 32; off > 0; off >>= 1) ss += __shfl_xor(ss, off, 64);
  float r = rsqrtf(ss * (1.0f / DS) + 1e-6f);
  const float4* nw = (const float4*)(norm_w + ((size_t)head * LL + layer) * DS);
  float4 w0 = nw[lane * 2], w1 = nw[lane * 2 + 1];
  uint4 o;
  o.x = pk2(v0.x * r * w0.x, v0.y * r * w0.y);
  o.y = pk2(v0.z * r * w0.z, v0.w * r * w0.w);
  o.z = pk2(v1.x * r * w1.x, v1.y * r * w1.y);
  o.w = pk2(v1.z * r * w1.z, v1.w * r * w1.w);
  *(uint4*)(xn + (size_t)gw * DS + (size_t)lane * 8) = o;
}

// ---------- 256x256 tile, BK=64, 8-wave, 4-phase pipelined bf16 GEMM ----------
// Same geometry/swizzle/ledger as round-6. Scheduling walls removed: ONE
// barrier per phase (at end), no sched_barrier except after counted vmcnt,
// no memory-clobber fences. Each phase = one scheduling region
// [ds_reads; stage; MFMA] -> compiler interleaves reads' service with MFMA
// via fine-grained lgkmcnt (the m97/m201 mechanism m141-style pinning broke).
// Stage plan (iter t): P0: A1(t+1) | P2: A0(t+2)+B0(t+2) | P3: B1(t+2).
// WAR safety: every stage target's prior reads retired >=2 phase-end barriers
// before the stage issues. Data-ready: end-P1 vmcnt(8) retires A1(t);
// end-P3 vmcnt(8) retires A0/B0/B1(t+1). Tails: vmcnt(0)/(2) as flagged.
template<int EPI>
__global__ __launch_bounds__(512, 2)
void gemm256_kernel(const unsigned short* __restrict__ A, int lda, int rstep,
                    const unsigned short* __restrict__ Bt, int ldb, long long b_hstride,
                    const float* __restrict__ bias, int bias_hstride,
                    const float* __restrict__ resid, int ldr,
                    void* __restrict__ Cv, int ldc, int K) {
  __shared__ unsigned short lds[2 * 2 * 256 * 64];  // 128 KiB
  const int tid = threadIdx.x;
  const int lane = tid & 63;
  const int wave = tid >> 6;
  const int wr = wave >> 2, wc = wave & 3;
  const int head = blockIdx.z;
  const int gx = gridDim.x;
  const int nwg = gx * gridDim.y;
  int wgid = blockIdx.y * gx + blockIdx.x;
  { int cpx = nwg >> 3; wgid = (wgid & 7) * cpx + (wgid >> 3); }  // bijective: nwg%8==0
  const int tn = wgid % gx, tm = wgid / gx;

  // ---- staging addressing (per-lane source, linear LDS dest) ----
  const int l3 = lane >> 3;                   // 0..7
  const int gslot = ((lane & 7) ^ l3) * 8;    // inverse-swizzled k offset (elements)
  const int mbase = wave * 8 + l3;
  const int nbase = (wave >> 2) * 64 + (wave & 3) * 8 + l3;
  const unsigned short* pA = A + ((size_t)(tm * 256 + mbase) * rstep + head) * lda + gslot;
  const unsigned short* pB = Bt + (size_t)head * b_hstride
                               + (size_t)(tn * 256 + nbase) * ldb + gslot;
  const size_t aBlk = (size_t)64 * rstep * lda;

  // ---- fragment read addressing ----
  const int physk0 = ((lane >> 4) ^ (lane & 7)) * 8;
  const int physk1 = ((4 + (lane >> 4)) ^ (lane & 7)) * 8;
  const int aRow = wr * 128 + (lane & 15);
  const int bRow = wc * 32 + (lane & 15);

  auto stageA = [&](unsigned short* dstA, int h, size_t kels) {
    #pragma unroll
    for (int i = 0; i < 2; ++i)
      __builtin_amdgcn_global_load_lds(
          (gptr_t)(pA + (size_t)(i * 2 + h) * aBlk + kels),
          (lptr_t)(dstA + ((i * 2 + h) * 64 + wave * 8) * 64), 16, 0, 0);
  };
  auto stageB = [&](unsigned short* dstB, int h, size_t kels) {
    #pragma unroll
    for (int i = 0; i < 2; ++i)
      __builtin_amdgcn_global_load_lds(
          (gptr_t)(pB + (size_t)(i * 128 + h * 32) * ldb + kels),
          (lptr_t)(dstB + (h * 128 + i * 64 + wave * 8) * 64), 16, 0, 0);
  };

  f32x4 acc[8][4];
  #pragma unroll
  for (int i = 0; i < 8; ++i)
    #pragma unroll
    for (int j = 0; j < 4; ++j) acc[i][j] = (f32x4){0.f, 0.f, 0.f, 0.f};
  short8 a[4][2], b[4][2];

  const int T = K >> 6;  // >= 2 for all shapes used
  // ---- prologue: tile0 {A0,B0,B1,A1} + tile1 {A0,B0,B1} = 14 load-instr ----
  stageA(lds, 0, 0);
  stageB(lds + 16384, 0, 0);
  stageB(lds + 16384, 1, 0);
  stageA(lds, 1, 0);
  stageA(lds + 32768, 0, 64);
  stageB(lds + 32768 + 16384, 0, 64);
  stageB(lds + 32768 + 16384, 1, 64);
  VMCNT8();   // A0(0),B0(0),B1(0) landed
  SB();
  BAR();

  for (int t = 0; t < T; ++t) {
    unsigned short* rA = lds + (t & 1) * 32768;
    unsigned short* rB = rA + 16384;
    unsigned short* nA = lds + ((t + 1) & 1) * 32768;
    const size_t k1 = (size_t)(t + 1) * 64;
    const size_t k2 = (size_t)(t + 2) * 64;
    const bool m1 = (t + 1 < T), m2 = (t + 2 < T);

    // ======== P0: read b01=B0(t), a=A0(t); stage A1(t+1); MFMA Q00 ========
    #pragma unroll
    for (int j = 0; j < 2; ++j) {
      b[j][0] = *(const short8*)&rB[(bRow + j * 16) * 64 + physk0];
      b[j][1] = *(const short8*)&rB[(bRow + j * 16) * 64 + physk1];
    }
    #pragma unroll
    for (int i = 0; i < 4; ++i) {
      a[i][0] = *(const short8*)&rA[(aRow + i * 16) * 64 + physk0];
      a[i][1] = *(const short8*)&rA[(aRow + i * 16) * 64 + physk1];
    }
    if (m1) stageA(nA, 1, k1);
    __builtin_amdgcn_s_setprio(1);
    #pragma unroll
    for (int i = 0; i < 4; ++i)
      #pragma unroll
      for (int j = 0; j < 2; ++j) {
        acc[i][j] = __builtin_amdgcn_mfma_f32_16x16x32_bf16(a[i][0], b[j][0], acc[i][j], 0, 0, 0);
        acc[i][j] = __builtin_amdgcn_mfma_f32_16x16x32_bf16(a[i][1], b[j][1], acc[i][j], 0, 0, 0);
      }
    __builtin_amdgcn_s_setprio(0);
    BAR();

    // ======== P1: read b23=B1(t); MFMA Q01; wait A1(t) ========
    #pragma unroll
    for (int j = 0; j < 2; ++j) {
      b[2 + j][0] = *(const short8*)&rB[(128 + bRow + j * 16) * 64 + physk0];
      b[2 + j][1] = *(const short8*)&rB[(128 + bRow + j * 16) * 64 + physk1];
    }
    __builtin_amdgcn_s_setprio(1);
    #pragma unroll
    for (int i = 0; i < 4; ++i)
      #pragma unroll
      for (int j = 0; j < 2; ++j) {
        acc[i][2 + j] = __builtin_amdgcn_mfma_f32_16x16x32_bf16(a[i][0], b[2 + j][0], acc[i][2 + j], 0, 0, 0);
        acc[i][2 + j] = __builtin_amdgcn_mfma_f32_16x16x32_bf16(a[i][1], b[2 + j][1], acc[i][2 + j], 0, 0, 0);
      }
    __builtin_amdgcn_s_setprio(0);
    if (m1) { VMCNT8(); } else { VMCNT0(); }
    SB();
    BAR();

    // ======== P2: read a'=A1(t); stage A0(t+2)+B0(t+2); MFMA Q11 ========
    #pragma unroll
    for (int i = 0; i < 4; ++i) {
      a[i][0] = *(const short8*)&rA[(aRow + (4 + i) * 16) * 64 + physk0];
      a[i][1] = *(const short8*)&rA[(aRow + (4 + i) * 16) * 64 + physk1];
    }
    if (m2) { stageA(rA, 0, k2); stageB(rB, 0, k2); }
    __builtin_amdgcn_s_setprio(1);
    #pragma unroll
    for (int i = 0; i < 4; ++i)
      #pragma unroll
      for (int j = 0; j < 2; ++j) {
        acc[4 + i][2 + j] = __builtin_amdgcn_mfma_f32_16x16x32_bf16(a[i][0], b[2 + j][0], acc[4 + i][2 + j], 0, 0, 0);
        acc[4 + i][2 + j] = __builtin_amdgcn_mfma_f32_16x16x32_bf16(a[i][1], b[2 + j][1], acc[4 + i][2 + j], 0, 0, 0);
      }
    __builtin_amdgcn_s_setprio(0);
    BAR();

    // ======== P3: stage B1(t+2); MFMA Q10; wait A0/B0/B1(t+1) ========
    if (m2) stageB(rB, 1, k2);
    __builtin_amdgcn_s_setprio(1);
    #pragma unroll
    for (int i = 0; i < 4; ++i)
      #pragma unroll
      for (int j = 0; j < 2; ++j) {
        acc[4 + i][j] = __builtin_amdgcn_mfma_f32_16x16x32_bf16(a[i][0], b[j][0], acc[4 + i][j], 0, 0, 0);
        acc[4 + i][j] = __builtin_amdgcn_mfma_f32_16x16x32_bf16(a[i][1], b[j][1], acc[4 + i][j], 0, 0, 0);
      }
    __builtin_amdgcn_s_setprio(0);
    if (m2) { VMCNT8(); } else if (m1) { VMCNT2(); }
    SB();
    BAR();
  }

  // ---- epilogue ----
  const float* bptr = bias + (size_t)head * bias_hstride;
  #pragma unroll
  for (int i = 0; i < 8; ++i) {
    #pragma unroll
    for (int j = 0; j < 4; ++j) {
      #pragma unroll
      for (int r = 0; r < 4; ++r) {
        int rowt = wr * 128 + i * 16 + (lane >> 4) * 4 + r;
        int colt = wc * 64 + j * 16 + (lane & 15);
        int col = tn * 256 + colt;
        size_t crow = (size_t)(tm * 256 + rowt) * rstep + head;
        float v = acc[i][j][r] + bptr[col];
        if (EPI == 1) {
          ((unsigned short*)Cv)[crow * (size_t)ldc + col] = f2bf(gelu_exact(v));
        } else if (EPI == 2) {
          v += resid[crow * (size_t)ldr + col];
          ((float*)Cv)[crow * (size_t)ldc + col] = v;
        } else {
          ((float*)Cv)[crow * (size_t)ldc + col] = v;
        }
      }
    }
  }
}

extern "C" void kernel_launch(void* const* d_in, const int* in_sizes, int n_in,
                              void* d_out, int out_size, void* d_ws, size_t ws_size,
                              hipStream_t stream) {
  const float* x         = (const float*)d_in[0];
  const float* id_in     = (const float*)d_in[1];
  const float* in_proj_w = (const float*)d_in[2];
  const float* in_proj_b = (const float*)d_in[3];
  const float* norm_w    = (const float*)d_in[4];
  const float* up_w      = (const float*)d_in[5];
  const float* up_b      = (const float*)d_in[6];
  const float* down_w    = (const float*)d_in[7];
  const float* down_b    = (const float*)d_in[8];
  const float* q1_w      = (const float*)d_in[9];
  const float* q1_b      = (const float*)d_in[10];
  const float* q2_w      = (const float*)d_in[11];
  const float* q2_b      = (const float*)d_in[12];
  const float* k1_w      = (const float*)d_in[13];
  const float* k1_b      = (const float*)d_in[14];
  const float* k2_w      = (const float*)d_in[15];
  const float* k2_b      = (const float*)d_in[16];
  float* out = (float*)d_out;

  char* ws = (char*)d_ws;
  unsigned short* x_bf  = (unsigned short*)ws; ws += (size_t)BHROWS * DSTEER * 2;  // 109 MB
  unsigned short* id_bf = (unsigned short*)ws; ws += (size_t)BHROWS * DID * 2;     // 8.4 MB
  float*          hbuf  = (float*)ws;          ws += (size_t)BHROWS * DS * 4;      // 67 MB
  unsigned short* xn    = (unsigned short*)ws; ws += (size_t)BHROWS * DS * 2;      // 33.5 MB
  unsigned short* hid   = (unsigned short*)ws; ws += (size_t)BHROWS * DHID * 2;    // 134 MB
  unsigned short* wbuf  = (unsigned short*)ws; ws += (size_t)HH * DHID * DS * 2;   // 67 MB (reused)

  // activations -> bf16
  cvt_bf16_kernel<<<2048, 256, 0, stream>>>((const float4*)x, (uint2*)x_bf,
                                            (long)BHROWS * DSTEER / 4);
  cvt_bf16_kernel<<<512, 256, 0, stream>>>((const float4*)id_in, (uint2*)id_bf,
                                           (long)BHROWS * DID / 4);

  // ---- q path ----
  transpose_cvt_kernel<<<dim3(2 * HDQ / 64, DSTEER / 32, 1), 256, 0, stream>>>(
      q1_w, 0, wbuf, 0, DSTEER, 2 * HDQ);
  gemm256_kernel<1><<<dim3(8, 128, 1), 512, 0, stream>>>(
      x_bf, DSTEER, 1, wbuf, DSTEER, 0, q1_b, 0, nullptr, 0, hid, 2 * HDQ, DSTEER);
  transpose_cvt_kernel<<<dim3(HDQ / 64, 2 * HDQ / 32, 1), 256, 0, stream>>>(
      q2_w, 0, wbuf, 0, 2 * HDQ, HDQ);
  gemm256_kernel<0><<<dim3(4, 128, 1), 512, 0, stream>>>(
      hid, 2 * HDQ, 1, wbuf, 2 * HDQ, 0, q2_b, 0, nullptr, 0, out + 512, 2560, 2 * HDQ);

  // ---- k path ----
  transpose_cvt_kernel<<<dim3(2 * HDQ / 64, DID / 32, 1), 256, 0, stream>>>(
      k1_w, 0, wbuf, 0, DID, 2 * HDQ);
  gemm256_kernel<1><<<dim3(8, 128, 1), 512, 0, stream>>>(
      id_bf, DID, 1, wbuf, DID, 0, k1_b, 0, nullptr, 0, hid, 2 * HDQ, DID);
  transpose_cvt_kernel<<<dim3(HDQ / 64, 2 * HDQ / 32, 1), 256, 0, stream>>>(
      k2_w, 0, wbuf, 0, 2 * HDQ, HDQ);
  gemm256_kernel<0><<<dim3(4, 128, 1), 512, 0, stream>>>(
      hid, 2 * HDQ, 1, wbuf, 2 * HDQ, 0, k2_b, 0, nullptr, 0, out + 1536, 2560, 2 * HDQ);

  // ---- content: in_proj (per-head) ----
  transpose_cvt_kernel<<<dim3(DS / 64, DSTEER / 32, HH), 256, 0, stream>>>(
      in_proj_w, (long long)DSTEER * DS, wbuf, (long long)DS * DSTEER, DSTEER, DS);
  gemm256_kernel<0><<<dim3(2, 4, 32), 512, 0, stream>>>(
      x_bf, DSTEER, HH, wbuf, DSTEER, (long long)DS * DSTEER, in_proj_b, DS,
      nullptr, 0, hbuf, DS, DSTEER);

  for (int i = 0; i < LL; i++) {
    rms_scale_kernel<<<8192, 256, 0, stream>>>(hbuf, norm_w, xn, i);
    transpose_cvt_kernel<<<dim3(DHID / 64, DS / 32, HH), 256, 0, stream>>>(
        up_w + (size_t)i * DS * DHID, (long long)LL * DS * DHID,
        wbuf, (long long)DHID * DS, DS, DHID);
    gemm256_kernel<1><<<dim3(8, 4, 32), 512, 0, stream>>>(
        xn, DS, HH, wbuf, DS, (long long)DHID * DS,
        up_b + (size_t)i * DHID, LL * DHID, nullptr, 0, hid, DHID, DS);
    transpose_cvt_kernel<<<dim3(DS / 64, DHID / 32, HH), 256, 0, stream>>>(
        down_w + (size_t)i * DHID * DS, (long long)LL * DHID * DS,
        wbuf, (long long)DS * DHID, DHID, DS);
    float* cout = (i < 2) ? hbuf : out;  // last layer -> out[:,0:512)
    int ldc = (i < 2) ? DS : 2560;
    gemm256_kernel<2><<<dim3(2, 4, 32), 512, 0, stream>>>(
        hid, DHID, HH, wbuf, DHID, (long long)DS * DHID,
        down_b + (size_t)i * DS, LL * DS, hbuf, DS, cout, ldc, DHID);
  }
}